// Round 7
// baseline (334.400 us; speedup 1.0000x reference)
//
#include <hip/hip_runtime.h>

typedef unsigned short u16;
typedef __attribute__((ext_vector_type(4))) float f32x4;
typedef __attribute__((ext_vector_type(16))) float f32x16;
typedef __attribute__((ext_vector_type(4))) unsigned short u16x4;
typedef __attribute__((ext_vector_type(4))) unsigned u32x4;
typedef __attribute__((ext_vector_type(2))) unsigned u32x2;
typedef __attribute__((ext_vector_type(8))) short bf16x8;

#define S_LEN 2048
#define NH 32
#define NKVH 8
#define DHEAD 128
#define HID 4096
#define KVW 1024
#define QKVW 6144

__device__ __forceinline__ u16 f2bf(float f) {
  unsigned u = __float_as_uint(f);
  u = u + 0x7fffu + ((u >> 16) & 1u);
  return (u16)(u >> 16);
}
__device__ __forceinline__ float bf2f(u16 h) {
  return __uint_as_float(((unsigned)h) << 16);
}
__device__ __forceinline__ void async16(void* lds, const void* g) {
  __builtin_amdgcn_global_load_lds((const __attribute__((address_space(1))) void*)g,
                                   (__attribute__((address_space(3))) void*)lds, 16, 0, 0);
}
__device__ __forceinline__ f32x4 mfma16(bf16x8 a, bf16x8 b, f32x4 c) {
  return __builtin_amdgcn_mfma_f32_16x16x32_bf16(a, b, c, 0, 0, 0);
}
__device__ __forceinline__ f32x16 mfma32(bf16x8 a, bf16x8 b, f32x16 c) {
  return __builtin_amdgcn_mfma_f32_32x32x16_bf16(a, b, c, 0, 0, 0);
}
__device__ __forceinline__ unsigned cvtpk(float a, float b) {
  unsigned r;
  asm("v_cvt_pk_bf16_f32 %0, %1, %2" : "=v"(r) : "v"(a), "v"(b));
  return r;
}
// intrinsic (not inline asm): the asm form with two "+v" operands holding the
// SAME value let the allocator coalesce them into ONE register -> NaN (R5).
__device__ __forceinline__ u32x2 pl32(unsigned a, unsigned b) {
  return __builtin_amdgcn_permlane32_swap(a, b, 0, 0);
}

// ---------------- x f32 -> bf16 ----------------
__global__ __launch_bounds__(256) void f2bf4_kernel(const float* __restrict__ in,
                                                    u16* __restrict__ out) {
  size_t i = ((size_t)blockIdx.x * 256 + threadIdx.x) * 4;
  f32x4 v = *(const f32x4*)(in + i);
  u16x4 o;
  o.x = f2bf(v.x); o.y = f2bf(v.y); o.z = f2bf(v.z); o.w = f2bf(v.w);
  *(u16x4*)(out + i) = o;
}

// -------- dequant fp4 codes [K][N] -> Wt [N][K] bf16 (transposed) --------
__global__ __launch_bounds__(256) void dequant_t_kernel(const int* __restrict__ codes,
                                                        const float* __restrict__ scales,
                                                        u16* __restrict__ Wt,
                                                        int K, int N) {
  __shared__ float tile[32][33];
  const int tx = threadIdx.x & 31, ty = threadIdx.x >> 5;
  const int k0 = blockIdx.x * 32, n0 = blockIdx.y * 32;
  const float sc = scales[(size_t)(k0 >> 7) * N + n0 + tx];
#pragma unroll
  for (int i = 0; i < 4; ++i) {
    int k = k0 + ty + i * 8;
    int c = codes[(size_t)k * N + n0 + tx];
    tile[ty + i * 8][tx] = ((float)c - 8.0f) * 0.5f * sc;
  }
  __syncthreads();
#pragma unroll
  for (int i = 0; i < 4; ++i) {
    int n = n0 + ty + i * 8;
    Wt[(size_t)n * K + k0 + tx] = f2bf(tile[tx][ty + i * 8]);
  }
}

// -------- 256 x NI*32 bf16 GEMM: C = A[M][K] * Bt[N][K]^T --------
// 512 thr, 8 waves (4M x 2N), per-wave 64 x NI*16, BK=64.
// XCD-ownership mapping: XCD g owns bn band {4g..4g+3} x all bm.
// A: LDS dbuf. B: LDS TRI-slot (staged for t+2).
// R7: 8-phase-per-2-tiles schedule (T3+T4 regime, guide m201 template):
// 4 phases per K-tile = {ds_read A-pair (+B on kk-entry) || stage piece ->
// barrier -> lgkmcnt(0) -> setprio MFMA cluster -> barrier}, counted
// vmcnt(NB) once per tile at the last phase. Per the regime-gate table,
// the per-phase double barrier creates the wave role-split that the old
// 2-fat-phase loop lacked (R1's reg-prefetch was null for this reason);
// MfmaUtil 45% -> predicted ~58%.
template <int NI, int OUTF32>
__global__ __launch_bounds__(512, 2) void gemm_w(const u16* __restrict__ A, int lda,
                                                 const u16* __restrict__ Bt, int ldb,
                                                 void* __restrict__ Cv, int ldc, int K) {
  constexpr int BN = NI * 32;
  constexpr int NB = NI / 2;              // B loads/thread/tile
  constexpr int BSLOT = BN * 128;         // bytes per B slot (BN rows x 128B)
  extern __shared__ char lds[];
  char* Bbase = lds + 65536;
  const int tid = threadIdx.x, w = tid >> 6, lane = tid & 63;
  const int lo = lane & 15, hi = lane >> 4;
  const int wm = w >> 1, wn = w & 1;
  const int id = blockIdx.x;
  const int g = id & 7, r = id >> 3;      // g == XCD id
  const int bm = r >> 2, bn = g * 4 + (r & 3);  // XCD owns a bn band: B HBM-once
  const int m0 = bm * 256, n0 = bn * BN;

  const int srow = tid >> 3, schunk = (tid & 7) ^ (srow & 7);
  const char* Ab = (const char*)(A + (size_t)(m0 + srow) * lda) + schunk * 16;
  const char* Bb = (const char*)(Bt + (size_t)(n0 + srow) * ldb) + schunk * 16;

  f32x4 acc[4][NI];
#pragma unroll
  for (int i = 0; i < 4; ++i)
#pragma unroll
    for (int j = 0; j < NI; ++j) acc[i][j] = (f32x4){0.f, 0.f, 0.f, 0.f};

  auto stageA = [&](int buf, int k1) {
#pragma unroll
    for (int u = 0; u < 2; ++u) {
      char* dst = lds + buf * 32768 + u * 8192 + w * 1024;
      async16(dst, Ab + ((size_t)(u * 64) * lda + k1) * 2);
      async16(dst + 16384, Ab + ((size_t)(u * 64 + 128) * lda + k1) * 2);
    }
  };
  auto stageB = [&](int slot, int k1) {
#pragma unroll
    for (int j = 0; j < NB; ++j)
      async16(Bbase + slot * BSLOT + j * 8192 + w * 1024,
              Bb + ((size_t)(j * 64) * ldb + k1) * 2);
  };

  // fragment addressing (read-side XOR matches pre-swizzled source)
  const int xm = (lo & 7) << 4;
  const int aro = (wm >> 1) * 16384 + (wm & 1) * 8192 + lo * 128;
  int bofs[NI];
#pragma unroll
  for (int ni = 0; ni < NI; ++ni) {
    int n = wn * (NI * 16) + ni * 16 + lo;
    bofs[ni] = (n >> 6) * 8192 + (n & 63) * 128;
  }

  // prologue: A(0)+B(0) must land; B(1) may fly
  stageA(0, 0);
  stageB(0, 0);
  stageB(1, 64);
  asm volatile("s_waitcnt vmcnt(%0)" ::"i"(NB) : "memory");
  __builtin_amdgcn_s_barrier();

  const int KT = K >> 6;
  int ab = 0, bb = 0;
  for (int t = 0; t < KT; ++t) {
    const char* As = lds + ab * 32768;
    const char* Bs = Bbase + bb * BSLOT;
    const bool m1 = t + 1 < KT, m2 = t + 2 < KT;
    int bs2 = bb + 2; if (bs2 >= 3) bs2 -= 3;
    bf16x8 Bf[NI];
#pragma unroll
    for (int q = 0; q < 4; ++q) {           // phase = (kk half, i half)
      const int kk = q >> 1, ih = q & 1;
      const int ck = (kk * 64 + hi * 16) ^ xm;
      // this phase's fragment reads
      bf16x8 Af0 = *(const bf16x8*)(As + aro + (ih * 2 + 0) * 2048 + ck);
      bf16x8 Af1 = *(const bf16x8*)(As + aro + (ih * 2 + 1) * 2048 + ck);
      if (ih == 0) {
#pragma unroll
        for (int ni = 0; ni < NI; ++ni)
          Bf[ni] = *(const bf16x8*)(Bs + bofs[ni] + ck);
      }
      // staged prefetch, distributed over phases
      if (q == 0 && m1) stageA(ab ^ 1, (t + 1) << 6);
      if (q == 2 && m2) stageB(bs2, (t + 2) << 6);
      __builtin_amdgcn_s_barrier();
      asm volatile("s_waitcnt lgkmcnt(0)" ::: "memory");
      __builtin_amdgcn_s_setprio(1);
#pragma unroll
      for (int ni = 0; ni < NI; ++ni) {
        acc[ih * 2 + 0][ni] = mfma16(Af0, Bf[ni], acc[ih * 2 + 0][ni]);
        acc[ih * 2 + 1][ni] = mfma16(Af1, Bf[ni], acc[ih * 2 + 1][ni]);
      }
      __builtin_amdgcn_s_setprio(0);
      if (q == 3 && m1) {  // per-tile gate: everything except B(t+2) landed
        if (m2) asm volatile("s_waitcnt vmcnt(%0)" ::"i"(NB) : "memory");
        else    asm volatile("s_waitcnt vmcnt(0)" ::: "memory");
      }
      __builtin_amdgcn_s_barrier();
    }
    ab ^= 1;
    if (++bb == 3) bb = 0;
  }
  // epilogue
#pragma unroll
  for (int mi = 0; mi < 4; ++mi)
#pragma unroll
    for (int ni = 0; ni < NI; ++ni) {
      size_t row = (size_t)(m0 + wm * 64 + mi * 16 + hi * 4);
      size_t col = (size_t)(n0 + wn * (NI * 16) + ni * 16 + lo);
#pragma unroll
      for (int rr = 0; rr < 4; ++rr) {
        size_t idx = (row + rr) * ldc + col;
        if (OUTF32) ((float*)Cv)[idx] = acc[mi][ni][rr];
        else ((u16*)Cv)[idx] = f2bf(acc[mi][ni][rr]);
      }
    }
}

// ---------------- RoPE tables: cos/sin per (s,d) ----------------
__global__ void rope_tab_kernel(float* __restrict__ ctab, float* __restrict__ stab) {
  int s = blockIdx.x, d = threadIdx.x;  // d in 0..63
  float inv = exp2f(-(float)d * 0.2076205059304601f);  // 10000^(-d/64)
  float ang = (float)s * inv;
  ctab[s * 64 + d] = cosf(ang);
  stab[s * 64 + d] = sinf(ang);
}

// ---------------- RoPE in-place on q,k parts of qkv ----------------
__global__ __launch_bounds__(256) void rope_kernel(u16* __restrict__ qkv,
                                                   const float* __restrict__ ctab,
                                                   const float* __restrict__ stab) {
  int s = blockIdx.x;
  int head = blockIdx.y * 4 + (threadIdx.x >> 6);
  int d = threadIdx.x & 63;
  int col = head < NH ? head * DHEAD + d : HID + (head - NH) * DHEAD + d;
  size_t base = (size_t)s * QKVW + col;
  float c = ctab[s * 64 + d], sn = stab[s * 64 + d];
  float x1 = bf2f(qkv[base]);
  float x2 = bf2f(qkv[base + 64]);
  qkv[base] = f2bf(x1 * c - x2 * sn);
  qkv[base + 64] = f2bf(x2 * c + x1 * sn);
}

// ---------------- V transpose: qkv v-part [S][1024] -> Vt [1024][S] ----------------
__global__ __launch_bounds__(256) void vtrans_kernel(const u16* __restrict__ qkv,
                                                     u16* __restrict__ Vt) {
  __shared__ u16 tile[32][33];
  const int tx = threadIdx.x & 31, ty = threadIdx.x >> 5;
  const int s0 = blockIdx.x * 32, c0 = blockIdx.y * 32;
#pragma unroll
  for (int i = 0; i < 4; ++i)
    tile[ty + i * 8][tx] = qkv[(size_t)(s0 + ty + i * 8) * QKVW + (HID + KVW) + c0 + tx];
  __syncthreads();
#pragma unroll
  for (int i = 0; i < 4; ++i)
    Vt[(size_t)(c0 + ty + i * 8) * S_LEN + s0 + tx] = tile[tx][ty + i * 8];
}

// ---------------- flash attention, causal, GQA 4:1 ----------------
// R6 structure kept (passed; ~93-94us, counters will reappear in top-5
// once the gemms drop below it): 32x32 swapped QK^T, in-register softmax
// (permlane32_swap), T12 in-reg P->bf16, 128-q blocks, complementary
// block pairing.
__global__ __launch_bounds__(256, 2) void attn_kernel(const u16* __restrict__ qkv,
                                                      const u16* __restrict__ Vt,
                                                      u16* __restrict__ attnO) {
  __shared__ alignas(16) u16 Ks[2][64 * 128];   // [kpos][d] 256B rows, swizzled
  __shared__ alignas(16) u16 Vs[2][128 * 64];   // [d][kpos] 128B rows, swizzled
  const int tid = threadIdx.x, w = tid >> 6, lane = tid & 63;
  const int l31 = lane & 31, hi5 = lane >> 5;
  const int bx = blockIdx.x, hd = blockIdx.y, kvh = hd >> 2;
  const int qb = (hd < 16) ? (15 - bx) : bx;    // complementary pairing
  const int qrow0 = qb * 128 + w * 32;
  const int qg = qrow0 + l31;                   // this lane's q row
  const u16* Kbase = qkv + HID + kvh * DHEAD;
  const u16* Vbase = Vt + (size_t)kvh * DHEAD * S_LEN;
  const int krow = w * 4 + (lane >> 4), kscn = lane & 15;   // staging coords
  const int vrow = w * 8 + (lane >> 3), vscn = lane & 7;

  auto stage = [&](int buf, int kt) {
#pragma unroll
    for (int i = 0; i < 4; ++i) {
      int kr = i * 16 + krow;
      async16((char*)&Ks[buf][0] + (i * 16 + w * 4) * 256,
              (const char*)(Kbase + (size_t)(kt * 64 + kr) * QKVW + (kscn ^ (kr & 7)) * 8));
      int vr = i * 32 + vrow;
      async16((char*)&Vs[buf][0] + (i * 32 + w * 8) * 128,
              (const char*)(Vbase + (size_t)vr * S_LEN + kt * 64 + (vscn ^ (vr & 7)) * 8));
    }
  };

  // Q fragments: lane holds Q[qg][dsl*16 + hi5*8 + j], scale folded in
  bf16x8 qf[8];
  {
    const u16* qp = qkv + (size_t)qg * QKVW + hd * DHEAD + hi5 * 8;
    const float qs = 0.08838834764831845f * 1.4426950408889634f;
#pragma unroll
    for (int dsl = 0; dsl < 8; ++dsl) {
      bf16x8 v = *(const bf16x8*)(qp + dsl * 16);
#pragma unroll
      for (int j = 0; j < 8; ++j) v[j] = (short)f2bf(bf2f((u16)v[j]) * qs);
      qf[dsl] = v;
    }
  }
  f32x16 oacc[4];  // O^T: col q = l31, row d = db*32 + (r&3)+8*(r>>2)+4*hi5
#pragma unroll
  for (int db = 0; db < 4; ++db)
#pragma unroll
    for (int r = 0; r < 16; ++r) oacc[db][r] = 0.f;
  float m_run = -1e30f, l_run = 0.f;

  const int nt = 2 * (qb + 1);
  stage(0, 0);
  __syncthreads();
  for (int kt = 0; kt < nt; ++kt) {
    const int cur = kt & 1;
    if (kt + 1 < nt) stage(cur ^ 1, kt + 1);
    if (kt * 64 <= qrow0 + 31) {  // wave-uniform: skip fully-masked tiles
      const char* Kc = (const char*)&Ks[cur][0];
      const char* Vc = (const char*)&Vs[cur][0];
      // K fragments: A[kpos][d]: kpos = blk*32 + l31, d = dsl*16 + hi5*8 + j
      bf16x8 kf0[8], kf1[8];
#pragma unroll
      for (int dsl = 0; dsl < 8; ++dsl) {
        kf0[dsl] = *(const bf16x8*)(Kc + l31 * 256 + ((2 * dsl + hi5) ^ (l31 & 7)) * 16);
        kf1[dsl] = *(const bf16x8*)(Kc + (32 + l31) * 256 +
                                    ((2 * dsl + hi5) ^ ((32 + l31) & 7)) * 16);
      }
      f32x16 st[2];
#pragma unroll
      for (int r = 0; r < 16; ++r) { st[0][r] = 0.f; st[1][r] = 0.f; }
      __builtin_amdgcn_s_setprio(1);
#pragma unroll
      for (int dsl = 0; dsl < 8; ++dsl) {
        st[0] = mfma32(kf0[dsl], qf[dsl], st[0]);
        st[1] = mfma32(kf1[dsl], qf[dsl], st[1]);
      }
      __builtin_amdgcn_s_setprio(0);
      if (kt >= 2 * qb) {  // diagonal: mask kpos > q
#pragma unroll
        for (int blk = 0; blk < 2; ++blk)
#pragma unroll
          for (int r = 0; r < 16; ++r) {
            int kpg = kt * 64 + blk * 32 + (r & 3) + 8 * (r >> 2) + 4 * hi5;
            st[blk][r] = (kpg <= qg) ? st[blk][r] : -1e30f;
          }
      }
      // row max: in-lane tree + one permlane32_swap (lane & lane+32 share q)
      float tm[16];
#pragma unroll
      for (int r = 0; r < 16; ++r) tm[r] = fmaxf(st[0][r], st[1][r]);
#pragma unroll
      for (int off = 8; off >= 1; off >>= 1)
#pragma unroll
        for (int r = 0; r < off; ++r) tm[r] = fmaxf(tm[r], tm[r + off]);
      float mloc;
      {
        u32x2 rr = pl32(__float_as_uint(tm[0]), __float_as_uint(tm[0]));
        mloc = fmaxf(__uint_as_float(rr.x), __uint_as_float(rr.y));
      }
      // T13 defer-max
      if (!__all(mloc - m_run <= 8.0f)) {
        float mn = fmaxf(m_run, mloc);
        float alpha = exp2f(m_run - mn);
        m_run = mn;
        l_run *= alpha;
#pragma unroll
        for (int db = 0; db < 4; ++db)
#pragma unroll
          for (int r = 0; r < 16; ++r) oacc[db][r] *= alpha;
      }
      // P = exp2(S - m), row sum
#pragma unroll
      for (int blk = 0; blk < 2; ++blk)
#pragma unroll
        for (int r = 0; r < 16; ++r) st[blk][r] = exp2f(st[blk][r] - m_run);
      float ts[16];
#pragma unroll
      for (int r = 0; r < 16; ++r) ts[r] = st[0][r] + st[1][r];
#pragma unroll
      for (int off = 8; off >= 1; off >>= 1)
#pragma unroll
        for (int r = 0; r < off; ++r) ts[r] += ts[r + off];
      {
        u32x2 rr = pl32(__float_as_uint(ts[0]), __float_as_uint(ts[0]));
        l_run += __uint_as_float(rr.x) + __uint_as_float(rr.y);
      }
      // T12: P -> bf16 B-fragments in-register (4 cvtpk + 2 swap per slice)
      bf16x8 pf[4];
#pragma unroll
      for (int s = 0; s < 4; ++s) {
        const int blk = s >> 1, r0 = (s & 1) * 8;
        unsigned a0 = cvtpk(st[blk][r0 + 0], st[blk][r0 + 1]);
        unsigned a1 = cvtpk(st[blk][r0 + 2], st[blk][r0 + 3]);
        unsigned b0 = cvtpk(st[blk][r0 + 4], st[blk][r0 + 5]);
        unsigned b1 = cvtpk(st[blk][r0 + 6], st[blk][r0 + 7]);
        u32x2 r0p = pl32(a0, b0);   // .x -> word0 (own-lo/partner-hi), .y -> word2
        u32x2 r1p = pl32(a1, b1);   // .x -> word1, .y -> word3
        u32x4 t; t.x = r0p.x; t.y = r1p.x; t.z = r0p.y; t.w = r1p.y;
        pf[s] = __builtin_bit_cast(bf16x8, t);
      }
      // PV: O^T += V^T * P^T ; A[d][kpos]: d = db*32+l31, kpos = s*16+hi5*8+j
      __builtin_amdgcn_s_setprio(1);
#pragma unroll
      for (int s = 0; s < 4; ++s) {
        bf16x8 vf[4];
#pragma unroll
        for (int db = 0; db < 4; ++db) {
          const int row = db * 32 + l31;
          vf[db] = *(const bf16x8*)(Vc + row * 128 + ((2 * s + hi5) ^ (row & 7)) * 16);
        }
#pragma unroll
        for (int db = 0; db < 4; ++db) oacc[db] = mfma32(vf[db], pf[s], oacc[db]);
      }
      __builtin_amdgcn_s_setprio(0);
    }
    __syncthreads();
  }
  // output: lane writes its q row; d = db*32 + 8*g + 4*hi5 + {0..3}
  float linv = 1.0f / l_run;
  u16* op = attnO + (size_t)qg * HID + hd * DHEAD;
#pragma unroll
  for (int db = 0; db < 4; ++db)
#pragma unroll
    for (int g = 0; g < 4; ++g) {
      u16x4 o4;
#pragma unroll
      for (int r2 = 0; r2 < 4; ++r2) o4[r2] = f2bf(oacc[db][g * 4 + r2] * linv);
      *(u16x4*)(op + db * 32 + 8 * g + 4 * hi5) = o4;
    }
}

extern "C" void kernel_launch(void* const* d_in, const int* in_sizes, int n_in,
                              void* d_out, int out_size, void* d_ws, size_t ws_size,
                              hipStream_t stream) {
  const float* x = (const float*)d_in[0];
  const int* qc = (const int*)d_in[1];
  const int* kc = (const int*)d_in[2];
  const int* vc = (const int*)d_in[3];
  const int* oc = (const int*)d_in[4];
  const float* qs = (const float*)d_in[5];
  const float* ks = (const float*)d_in[6];
  const float* vs = (const float*)d_in[7];
  const float* os = (const float*)d_in[8];
  float* out = (float*)d_out;
  char* ws = (char*)d_ws;

  u16* xb    = (u16*)(ws);                    // 2048*4096*2   = 16,777,216
  u16* qkv   = (u16*)(ws + 16777216);         // 2048*6144*2   = 25,165,824
  u16* attnb = (u16*)(ws + 41943040);         // 2048*4096*2   = 16,777,216
  u16* Vt    = (u16*)(ws + 58720256);         // 1024*2048*2   =  4,194,304
  u16* Wbig  = (u16*)(ws + 62914560);         // 6144*4096*2   = 50,331,648 (reused for Wo^T)
  float* ctab = (float*)Vt;                   // rope tables live in Vt region pre-vtrans
  float* stab = (float*)(ws + 58720256 + 524288);

  // x -> bf16
  f2bf4_kernel<<<8192, 256, 0, stream>>>(x, xb);
  // dequant W^T (q | k | v) into Wbig rows [0,4096) / [4096,5120) / [5120,6144)
  dequant_t_kernel<<<dim3(128, 128), 256, 0, stream>>>(qc, qs, Wbig, HID, HID);
  dequant_t_kernel<<<dim3(128, 32), 256, 0, stream>>>(kc, ks, Wbig + (size_t)HID * HID, HID, KVW);
  dequant_t_kernel<<<dim3(128, 32), 256, 0, stream>>>(vc, vs, Wbig + (size_t)(HID + KVW) * HID, HID, KVW);
  // rope tables
  rope_tab_kernel<<<2048, 64, 0, stream>>>(ctab, stab);
  // qkv = xb @ Wqkv : BN=192 (NI=6), grid 256, XCD-owns-bn-band mapping
  gemm_w<6, 0><<<256, 512, 139264, stream>>>(xb, HID, Wbig, HID, qkv, QKVW, HID);
  // RoPE q,k in place
  rope_kernel<<<dim3(S_LEN, (NH + NKVH) / 4), 256, 0, stream>>>(qkv, ctab, stab);
  // V^T
  vtrans_kernel<<<dim3(64, 32), 256, 0, stream>>>(qkv, Vt);
  // attention (32x32 in-register-softmax structure)
  attn_kernel<<<dim3(16, 32), 256, 0, stream>>>(qkv, Vt, attnb);
  // dequant Wo^T (reuse Wbig)
  dequant_t_kernel<<<dim3(128, 128), 256, 0, stream>>>(oc, os, Wbig, HID, HID);
  // out = attnb @ Wo : BN=128 (NI=4), grid 256, XCD-owns-bn-band mapping
  gemm_w<4, 1><<<256, 512, 114688, stream>>>(attnb, HID, Wbig, HID, out, HID, HID);
}

// Round 8
// 318.189 us; speedup vs baseline: 1.0509x; 1.0509x over previous
//
#include <hip/hip_runtime.h>

typedef unsigned short u16;
typedef __attribute__((ext_vector_type(4))) float f32x4;
typedef __attribute__((ext_vector_type(4))) unsigned short u16x4;
typedef __attribute__((ext_vector_type(8))) short bf16x8;

#define S_LEN 2048
#define NH 32
#define NKVH 8
#define DHEAD 128
#define HID 4096
#define KVW 1024
#define QKVW 6144

__device__ __forceinline__ u16 f2bf(float f) {
  unsigned u = __float_as_uint(f);
  u = u + 0x7fffu + ((u >> 16) & 1u);
  return (u16)(u >> 16);
}
__device__ __forceinline__ float bf2f(u16 h) {
  return __uint_as_float(((unsigned)h) << 16);
}
__device__ __forceinline__ void async16(void* lds, const void* g) {
  __builtin_amdgcn_global_load_lds((const __attribute__((address_space(1))) void*)g,
                                   (__attribute__((address_space(3))) void*)lds, 16, 0, 0);
}
__device__ __forceinline__ f32x4 mfma16(bf16x8 a, bf16x8 b, f32x4 c) {
  return __builtin_amdgcn_mfma_f32_16x16x32_bf16(a, b, c, 0, 0, 0);
}
__device__ __forceinline__ unsigned cvtpk(float a, float b) {
  unsigned r;
  asm("v_cvt_pk_bf16_f32 %0, %1, %2" : "=v"(r) : "v"(a), "v"(b));
  return r;
}

// ---------------- x f32 -> bf16 ----------------
__global__ __launch_bounds__(256) void f2bf4_kernel(const float* __restrict__ in,
                                                    u16* __restrict__ out) {
  size_t i = ((size_t)blockIdx.x * 256 + threadIdx.x) * 4;
  f32x4 v = *(const f32x4*)(in + i);
  u16x4 o;
  o.x = f2bf(v.x); o.y = f2bf(v.y); o.z = f2bf(v.z); o.w = f2bf(v.w);
  *(u16x4*)(out + i) = o;
}

// -------- dequant fp4 codes [K][N] -> Wt [N][K] bf16 (transposed) --------
__global__ __launch_bounds__(256) void dequant_t_kernel(const int* __restrict__ codes,
                                                        const float* __restrict__ scales,
                                                        u16* __restrict__ Wt,
                                                        int K, int N) {
  __shared__ float tile[32][33];
  const int tx = threadIdx.x & 31, ty = threadIdx.x >> 5;
  const int k0 = blockIdx.x * 32, n0 = blockIdx.y * 32;
  const float sc = scales[(size_t)(k0 >> 7) * N + n0 + tx];
#pragma unroll
  for (int i = 0; i < 4; ++i) {
    int k = k0 + ty + i * 8;
    int c = codes[(size_t)k * N + n0 + tx];
    tile[ty + i * 8][tx] = ((float)c - 8.0f) * 0.5f * sc;
  }
  __syncthreads();
#pragma unroll
  for (int i = 0; i < 4; ++i) {
    int n = n0 + ty + i * 8;
    Wt[(size_t)n * K + k0 + tx] = f2bf(tile[tx][ty + i * 8]);
  }
}

// -------- 256 x NI*32 fat-phase bf16 GEMM: C = A[M][K] * Bt[N][K]^T --------
// R8: reverted to the R1/R6 version (95.3us, MfmaUtil 45%). R7's 4-phase
// per-tile barrier schedule REGRESSED to 106.8us / 40% — the m201 8-phase
// template's gains don't transfer as a piecemeal graft at this geometry.
template <int NI, int OUTF32>
__global__ __launch_bounds__(512, 2) void gemm_w(const u16* __restrict__ A, int lda,
                                                 const u16* __restrict__ Bt, int ldb,
                                                 void* __restrict__ Cv, int ldc, int K) {
  constexpr int BN = NI * 32;
  constexpr int NB = NI / 2;              // B loads/thread/tile
  constexpr int BSLOT = BN * 128;         // bytes per B slot (BN rows x 128B)
  extern __shared__ char lds[];
  char* Bbase = lds + 65536;
  const int tid = threadIdx.x, w = tid >> 6, lane = tid & 63;
  const int lo = lane & 15, hi = lane >> 4;
  const int wm = w >> 1, wn = w & 1;
  const int id = blockIdx.x;
  const int g = id & 7, r = id >> 3;      // g == XCD id
  const int bm = r >> 2, bn = g * 4 + (r & 3);  // XCD owns a bn band: B HBM-once
  const int m0 = bm * 256, n0 = bn * BN;

  const int srow = tid >> 3, schunk = (tid & 7) ^ (srow & 7);
  const char* Ab = (const char*)(A + (size_t)(m0 + srow) * lda) + schunk * 16;
  const char* Bb = (const char*)(Bt + (size_t)(n0 + srow) * ldb) + schunk * 16;

  f32x4 acc[4][NI];
#pragma unroll
  for (int i = 0; i < 4; ++i)
#pragma unroll
    for (int j = 0; j < NI; ++j) acc[i][j] = (f32x4){0.f, 0.f, 0.f, 0.f};

  auto stageA = [&](int buf, int k1) {
#pragma unroll
    for (int u = 0; u < 2; ++u) {
      char* dst = lds + buf * 32768 + u * 8192 + w * 1024;
      async16(dst, Ab + ((size_t)(u * 64) * lda + k1) * 2);
      async16(dst + 16384, Ab + ((size_t)(u * 64 + 128) * lda + k1) * 2);
    }
  };
  auto stageB = [&](int slot, int k1) {
#pragma unroll
    for (int j = 0; j < NB; ++j)
      async16(Bbase + slot * BSLOT + j * 8192 + w * 1024,
              Bb + ((size_t)(j * 64) * ldb + k1) * 2);
  };

  // fragment addressing (read-side XOR matches pre-swizzled source)
  const int xm = (lo & 7) << 4;
  const int aro = (wm >> 1) * 16384 + (wm & 1) * 8192 + lo * 128;
  int bofs[NI];
#pragma unroll
  for (int ni = 0; ni < NI; ++ni) {
    int n = wn * (NI * 16) + ni * 16 + lo;
    bofs[ni] = (n >> 6) * 8192 + (n & 63) * 128;
  }

  // fragment loader: kk selects the 64-byte K-half within the staged tile
  auto ldfrags = [&](const char* As, const char* Bs, int kk, bf16x8* Afo, bf16x8* Bfo) {
    const int ck = (kk * 64 + hi * 16) ^ xm;
#pragma unroll
    for (int i = 0; i < 4; ++i) Afo[i] = *(const bf16x8*)(As + aro + i * 2048 + ck);
#pragma unroll
    for (int ni = 0; ni < NI; ++ni) Bfo[ni] = *(const bf16x8*)(Bs + bofs[ni] + ck);
  };

  // prologue: A(0)+B(0) must land; B(1) may fly
  stageA(0, 0);
  stageB(0, 0);
  stageB(1, 64);
  asm volatile("s_waitcnt vmcnt(%0)" ::"i"(NB) : "memory");
  __builtin_amdgcn_s_barrier();

  bf16x8 Afc[4], Bfc[NI], Afn[4], Bfn[NI];
  ldfrags(lds, Bbase, 0, Afc, Bfc);  // tile 0, kk=0 into cur set

  const int KT = K >> 6;
  int ab = 0, bb = 0;
  for (int t = 0; t < KT; ++t) {
    const char* As = lds + ab * 32768;
    const char* Bs = Bbase + bb * BSLOT;
    const bool m1 = t + 1 < KT, m2 = t + 2 < KT;
    int bs2 = bb + 2; if (bs2 >= 3) bs2 -= 3;
    int bn1 = bb + 1; if (bn1 >= 3) bn1 -= 3;
    // phase 0: stage A(t+1); prefetch kk=1 frags; MFMA kk=0 (already in regs)
    if (m1) stageA(ab ^ 1, (t + 1) << 6);
    ldfrags(As, Bs, 1, Afn, Bfn);
    __builtin_amdgcn_sched_barrier(0);  // keep prefetch ABOVE the MFMA cluster
    __builtin_amdgcn_s_setprio(1);
#pragma unroll
    for (int i = 0; i < 4; ++i)
#pragma unroll
      for (int ni = 0; ni < NI; ++ni)
        acc[i][ni] = mfma16(Afc[i], Bfc[ni], acc[i][ni]);
    __builtin_amdgcn_s_setprio(0);
    // phase 1: stage B(t+2); MFMA kk=1; gate; prefetch next tile's kk=0 frags
    if (m2) stageB(bs2, (t + 2) << 6);
    __builtin_amdgcn_s_setprio(1);
#pragma unroll
    for (int i = 0; i < 4; ++i)
#pragma unroll
      for (int ni = 0; ni < NI; ++ni)
        acc[i][ni] = mfma16(Afn[i], Bfn[ni], acc[i][ni]);
    __builtin_amdgcn_s_setprio(0);
    if (m1) {  // single per-tile gate: everything except B(t+2) landed
      if (m2) asm volatile("s_waitcnt vmcnt(%0)" ::"i"(NB) : "memory");
      else    asm volatile("s_waitcnt vmcnt(0)" ::: "memory");
      __builtin_amdgcn_s_barrier();
      ldfrags(lds + (ab ^ 1) * 32768, Bbase + bn1 * BSLOT, 0, Afc, Bfc);
      __builtin_amdgcn_sched_barrier(0);  // don't sink into next iteration
    }
    ab ^= 1;
    if (++bb == 3) bb = 0;
  }
  // epilogue
#pragma unroll
  for (int mi = 0; mi < 4; ++mi)
#pragma unroll
    for (int ni = 0; ni < NI; ++ni) {
      size_t row = (size_t)(m0 + wm * 64 + mi * 16 + hi * 4);
      size_t col = (size_t)(n0 + wn * (NI * 16) + ni * 16 + lo);
#pragma unroll
      for (int rr = 0; rr < 4; ++rr) {
        size_t idx = (row + rr) * ldc + col;
        if (OUTF32) ((float*)Cv)[idx] = acc[mi][ni][rr];
        else ((u16*)Cv)[idx] = f2bf(acc[mi][ni][rr]);
      }
    }
}

// ---------------- RoPE tables: cos/sin per (s,d) ----------------
__global__ void rope_tab_kernel(float* __restrict__ ctab, float* __restrict__ stab) {
  int s = blockIdx.x, d = threadIdx.x;  // d in 0..63
  float inv = exp2f(-(float)d * 0.2076205059304601f);  // 10000^(-d/64)
  float ang = (float)s * inv;
  ctab[s * 64 + d] = cosf(ang);
  stab[s * 64 + d] = sinf(ang);
}

// ---------------- RoPE in-place on q,k parts of qkv ----------------
__global__ __launch_bounds__(256) void rope_kernel(u16* __restrict__ qkv,
                                                   const float* __restrict__ ctab,
                                                   const float* __restrict__ stab) {
  int s = blockIdx.x;
  int head = blockIdx.y * 4 + (threadIdx.x >> 6);
  int d = threadIdx.x & 63;
  int col = head < NH ? head * DHEAD + d : HID + (head - NH) * DHEAD + d;
  size_t base = (size_t)s * QKVW + col;
  float c = ctab[s * 64 + d], sn = stab[s * 64 + d];
  float x1 = bf2f(qkv[base]);
  float x2 = bf2f(qkv[base + 64]);
  qkv[base] = f2bf(x1 * c - x2 * sn);
  qkv[base + 64] = f2bf(x2 * c + x1 * sn);
}

// ---------------- V transpose: qkv v-part [S][1024] -> Vt [1024][S] ----------------
__global__ __launch_bounds__(256) void vtrans_kernel(const u16* __restrict__ qkv,
                                                     u16* __restrict__ Vt) {
  __shared__ u16 tile[32][33];
  const int tx = threadIdx.x & 31, ty = threadIdx.x >> 5;
  const int s0 = blockIdx.x * 32, c0 = blockIdx.y * 32;
#pragma unroll
  for (int i = 0; i < 4; ++i)
    tile[ty + i * 8][tx] = qkv[(size_t)(s0 + ty + i * 8) * QKVW + (HID + KVW) + c0 + tx];
  __syncthreads();
#pragma unroll
  for (int i = 0; i < 4; ++i)
    Vt[(size_t)(c0 + ty + i * 8) * S_LEN + s0 + tx] = tile[tx][ty + i * 8];
}

// ---------------- flash attention, causal, GQA 4:1 ----------------
// R8: OCCUPANCY fix. Four structurally different attn kernels (R0/R2/R4/R6)
// all landed 93-100us; per-CU pipe sums (MFMA 34K + VALU 92K + DS ~100K cyc)
// are well under the 230K wall -> latency-bound at 2 blocks/CU (2 waves/SIMD),
// with __syncthreads' implicit vmcnt(0) draining the prefetch every iter.
// Fix: R0's lean 88-VGPR structure, single-buffered K/V, Ps stride 44->32
// with XOR swizzle -> LDS 76800 -> 40960 B -> 4 blocks/CU; launch_bounds
// (256,4) -> 16 waves/CU, 4 waves/SIMD from 4 INDEPENDENT blocks. Stage
// latency per iter is now covered by the other 3 blocks' compute (TLP),
// so pipelining is deliberately traded away for occupancy.
__global__ __launch_bounds__(256, 4) void attn_kernel(const u16* __restrict__ qkv,
                                                      const u16* __restrict__ Vt,
                                                      u16* __restrict__ attnO) {
  __shared__ alignas(16) u16 Ks[64 * 128];          // [kpos][d] 256B rows, swizzled
  __shared__ alignas(16) u16 Vs[128 * 64];          // [d][kpos] 128B rows, swizzled
  __shared__ alignas(16) unsigned Ps32[4][16][32];  // per-wave P pairs, XOR-swizzled
  const int tid = threadIdx.x, w = tid >> 6, lane = tid & 63;
  const int lo = lane & 15, hi = lane >> 4;
  const unsigned pxor = (unsigned)((lo & 7) << 2);  // Ps bank-spread (bits 2-4)
  const int bx = blockIdx.x, h = blockIdx.y, kvh = h >> 2;
  const u16* Kbase = qkv + HID + kvh * DHEAD;
  const u16* Vbase = Vt + (size_t)kvh * DHEAD * S_LEN;
  const int krow = w * 4 + hi;           // + i*16 ; K stage row
  const int kscn = lo;                   // ^ (row&7)
  const int vrow = w * 8 + (lane >> 3);  // + i*32 ; V stage row
  const int vscn = lane & 7;

#pragma unroll 1
  for (int pass = 0; pass < 2; ++pass) {
    const int qb = pass == 0 ? (31 - bx) : bx;
    const int qrow0 = qb * 64 + w * 16;
    // Q fragments with 1/sqrt(D)*log2(e) folded in
    bf16x8 qf[4];
    {
      const u16* qp = qkv + (size_t)(qrow0 + lo) * QKVW + h * DHEAD;
      const float qs = 0.08838834764831845f * 1.4426950408889634f;
#pragma unroll
      for (int dc = 0; dc < 4; ++dc) {
        bf16x8 v = *(const bf16x8*)(qp + dc * 32 + hi * 8);
#pragma unroll
        for (int j = 0; j < 8; ++j) v[j] = (short)f2bf(bf2f((u16)v[j]) * qs);
        qf[dc] = v;
      }
    }
    f32x4 oacc[8];  // O^T: row d = dt*16+4*hi+r, col q = lo
#pragma unroll
    for (int i = 0; i < 8; ++i) oacc[i] = (f32x4){0.f, 0.f, 0.f, 0.f};
    float m_run = -1e30f, l_run = 0.f;

    const int nt = qb + 1;
    for (int kt = 0; kt < nt; ++kt) {
      // stage tile kt into the (single) buffers
#pragma unroll
      for (int i = 0; i < 4; ++i) {
        int kr = i * 16 + krow;
        async16((char*)&Ks[0] + (i * 16 + w * 4) * 256,
                (const char*)(Kbase + (size_t)(kt * 64 + kr) * QKVW + (kscn ^ (kr & 7)) * 8));
        int vr = i * 32 + vrow;
        async16((char*)&Vs[0] + (i * 32 + w * 8) * 128,
                (const char*)(Vbase + (size_t)vr * S_LEN + kt * 64 + (vscn ^ (vr & 7)) * 8));
      }
      __syncthreads();  // implicit vmcnt(0): staged data landed for all waves
      // QK^T swapped: st[t] = S^T[kpos=16t+4hi+r][q=lo]
      f32x4 st[4];
#pragma unroll
      for (int t = 0; t < 4; ++t) st[t] = (f32x4){0.f, 0.f, 0.f, 0.f};
#pragma unroll
      for (int t = 0; t < 4; ++t) {
        int kq = t * 16 + lo;
#pragma unroll
        for (int dc = 0; dc < 4; ++dc) {
          bf16x8 kf = *(const bf16x8*)((const char*)&Ks[0] + kq * 256 +
                                       (((dc << 2) + hi) ^ (kq & 7)) * 16);
          st[t] = mfma16(kf, qf[dc], st[t]);
        }
      }
      if (kt == qb) {  // diagonal tile: causal mask (kpos<=q)
#pragma unroll
        for (int t = 0; t < 4; ++t)
#pragma unroll
          for (int r = 0; r < 4; ++r) {
            int kposl = t * 16 + 4 * hi + r;
            st[t][r] = (kposl <= w * 16 + lo) ? st[t][r] : -1e30f;
          }
      }
      // online softmax (log2 domain), per-lane stats for q=lo
      float mloc = st[0][0];
#pragma unroll
      for (int t = 0; t < 4; ++t)
#pragma unroll
        for (int r = 0; r < 4; ++r) mloc = fmaxf(mloc, st[t][r]);
      mloc = fmaxf(mloc, __shfl_xor(mloc, 16, 64));
      mloc = fmaxf(mloc, __shfl_xor(mloc, 32, 64));
      // T13 defer-max: skip rescale while max growth <= 8 (P bounded by 2^8)
      if (!__all(mloc - m_run <= 8.0f)) {
        float mn = fmaxf(m_run, mloc);
        float alpha = exp2f(m_run - mn);
        m_run = mn;
        l_run *= alpha;
#pragma unroll
        for (int dt = 0; dt < 8; ++dt)
#pragma unroll
          for (int r = 0; r < 4; ++r) oacc[dt][r] *= alpha;
      }
      float psum = 0.f;
#pragma unroll
      for (int t = 0; t < 4; ++t)
#pragma unroll
        for (int r = 0; r < 4; ++r) {
          float p = exp2f(st[t][r] - m_run);
          st[t][r] = p;
          psum += p;
        }
      psum += __shfl_xor(psum, 16, 64);
      psum += __shfl_xor(psum, 32, 64);
      l_run += psum;
      // pack P -> bf16 pairs, write P[q][kpos] to per-wave LDS (XOR-swizzled)
#pragma unroll
      for (int t = 0; t < 4; ++t)
#pragma unroll
        for (int rp = 0; rp < 2; ++rp)
          Ps32[w][lo][(unsigned)(8 * t + 2 * hi + rp) ^ pxor] =
              cvtpk(st[t][2 * rp], st[t][2 * rp + 1]);
      // PV: O^T += V^T_tile * P^T
      bf16x8 pf[2];
#pragma unroll
      for (int kc = 0; kc < 2; ++kc)
        pf[kc] = *(const bf16x8*)&Ps32[w][lo][(unsigned)(kc * 16 + hi * 4) ^ pxor];
#pragma unroll
      for (int dt = 0; dt < 8; ++dt) {
        int d = dt * 16 + lo;
#pragma unroll
        for (int kc = 0; kc < 2; ++kc) {
          bf16x8 vf = *(const bf16x8*)((const char*)&Vs[0] + d * 128 +
                                       (((kc << 2) + hi) ^ (d & 7)) * 16);
          oacc[dt] = mfma16(vf, pf[kc], oacc[dt]);
        }
      }
      __syncthreads();  // all reads done before next iter's restage
    }
    // output
    float linv = 1.0f / l_run;
    u16* op = attnO + (size_t)(qrow0 + lo) * HID + h * DHEAD;
#pragma unroll
    for (int dt = 0; dt < 8; ++dt) {
      u16x4 o4;
#pragma unroll
      for (int r = 0; r < 4; ++r) o4[r] = f2bf(oacc[dt][r] * linv);
      *(u16x4*)(op + dt * 16 + 4 * hi) = o4;
    }
  }
}

extern "C" void kernel_launch(void* const* d_in, const int* in_sizes, int n_in,
                              void* d_out, int out_size, void* d_ws, size_t ws_size,
                              hipStream_t stream) {
  const float* x = (const float*)d_in[0];
  const int* qc = (const int*)d_in[1];
  const int* kc = (const int*)d_in[2];
  const int* vc = (const int*)d_in[3];
  const int* oc = (const int*)d_in[4];
  const float* qs = (const float*)d_in[5];
  const float* ks = (const float*)d_in[6];
  const float* vs = (const float*)d_in[7];
  const float* os = (const float*)d_in[8];
  float* out = (float*)d_out;
  char* ws = (char*)d_ws;

  u16* xb    = (u16*)(ws);                    // 2048*4096*2   = 16,777,216
  u16* qkv   = (u16*)(ws + 16777216);         // 2048*6144*2   = 25,165,824
  u16* attnb = (u16*)(ws + 41943040);         // 2048*4096*2   = 16,777,216
  u16* Vt    = (u16*)(ws + 58720256);         // 1024*2048*2   =  4,194,304
  u16* Wbig  = (u16*)(ws + 62914560);         // 6144*4096*2   = 50,331,648 (reused for Wo^T)
  float* ctab = (float*)Vt;                   // rope tables live in Vt region pre-vtrans
  float* stab = (float*)(ws + 58720256 + 524288);

  // x -> bf16
  f2bf4_kernel<<<8192, 256, 0, stream>>>(x, xb);
  // dequant W^T (q | k | v) into Wbig rows [0,4096) / [4096,5120) / [5120,6144)
  dequant_t_kernel<<<dim3(128, 128), 256, 0, stream>>>(qc, qs, Wbig, HID, HID);
  dequant_t_kernel<<<dim3(128, 32), 256, 0, stream>>>(kc, ks, Wbig + (size_t)HID * HID, HID, KVW);
  dequant_t_kernel<<<dim3(128, 32), 256, 0, stream>>>(vc, vs, Wbig + (size_t)(HID + KVW) * HID, HID, KVW);
  // rope tables
  rope_tab_kernel<<<2048, 64, 0, stream>>>(ctab, stab);
  // qkv = xb @ Wqkv : BN=192 (NI=6), grid 256, XCD-owns-bn-band mapping
  gemm_w<6, 0><<<256, 512, 139264, stream>>>(xb, HID, Wbig, HID, qkv, QKVW, HID);
  // RoPE q,k in place
  rope_kernel<<<dim3(S_LEN, (NH + NKVH) / 4), 256, 0, stream>>>(qkv, ctab, stab);
  // V^T
  vtrans_kernel<<<dim3(64, 32), 256, 0, stream>>>(qkv, Vt);
  // attention (4 blocks/CU, single-buffered staging)
  attn_kernel<<<dim3(16, 32), 256, 0, stream>>>(qkv, Vt, attnb);
  // dequant Wo^T (reuse Wbig)
  dequant_t_kernel<<<dim3(128, 128), 256, 0, stream>>>(oc, os, Wbig, HID, HID);
  // out = attnb @ Wo : BN=128 (NI=4), grid 256, XCD-owns-bn-band mapping
  gemm_w<4, 1><<<256, 512, 114688, stream>>>(attnb, HID, Wbig, HID, out, HID, HID);
}